// Round 2
// 889.396 us; speedup vs baseline: 1.0027x; 1.0027x over previous
//
#include <hip/hip_runtime.h>

#define EPS 1e-5f

typedef _Float16 half8_t __attribute__((ext_vector_type(8)));
typedef _Float16 half4_t __attribute__((ext_vector_type(4)));
typedef float    float4_t __attribute__((ext_vector_type(4)));

// Fast tanh-form GELU via exp2: gelu(v) = v * sigmoid(2t), t = 0.79788456*v*(1+0.044715 v^2).
// arg = -2*t*log2(e) = v * (-2.3022078 - 0.10294322 v^2).  Max |err| vs exact erf-GELU ~5e-4.
// Saturates correctly for |v| large (exp2 -> 0 or inf -> rcp -> 0).
__device__ __forceinline__ float gelu_f(float v) {
  float u2 = v * v;
  float a  = __builtin_fmaf(u2, -0.10294322f, -2.3022078f);
  float e  = __builtin_amdgcn_exp2f(v * a);
  return v * __builtin_amdgcn_rcpf(1.0f + e);
}

// DPP-based sum over the 16 lanes of a row (lanes l&15 hold d=0..15).
template<int CTRL>
__device__ __forceinline__ float dpp_add(float v) {
  int j = __builtin_amdgcn_update_dpp(0, __float_as_int(v), CTRL, 0xF, 0xF, true);
  return v + __int_as_float(j);
}
__device__ __forceinline__ float rsum16(float v) {
  v = dpp_add<0xB1>(v);   // quad_perm {1,0,3,2}  : xor 1
  v = dpp_add<0x4E>(v);   // quad_perm {2,3,0,1}  : xor 2
  v = dpp_add<0x124>(v);  // row_ror:4
  v = dpp_add<0x128>(v);  // row_ror:8
  return v;
}

// ---------------- weight conversion (fp32 -> fp16, reordered) ----------------
// kvw rows r in [0,256): h=r>>5, rr=r&31 -> qkv row h*48+16+rr  (k then v per head)
//   LN-mean folding: subtract the per-head 16-row mean of the k (or v) block, so
//   k' = W'x is exactly centered and LN needs only the sum-of-squares stat.
// qw  rows r in [0,128): h=r>>4, d=r&15 -> qkv row h*48+d
__global__ __launch_bounds__(256)
void k_wconv(const float* __restrict__ qkvw, const float* __restrict__ o1w,
             const float* __restrict__ o2w, _Float16* __restrict__ kvw,
             _Float16* __restrict__ qw, _Float16* __restrict__ o1h,
             _Float16* __restrict__ o2h) {
  int t = blockIdx.x * 256 + threadIdx.x;        // 0..81919
  if (t < 32768) {
    int r = t >> 7, c = t & 127;
    int h = r >> 5, rr = r & 31;
    int src = h * 48 + 16 + rr;
    int mb  = h * 48 + 16 + (rr & 16);           // base row of this k- or v-block
    float s = 0.0f;
#pragma unroll
    for (int d = 0; d < 16; d++) s += qkvw[(mb + d) * 128 + c];
    kvw[t] = (_Float16)(qkvw[src * 128 + c] - 0.0625f * s);
  } else if (t < 49152) {
    int i = t - 32768;
    int r = i >> 7, c = i & 127;
    int src = (r >> 4) * 48 + (r & 15);
    qw[i] = (_Float16)qkvw[src * 128 + c];
  } else if (t < 65536) {
    int i = t - 49152;
    o1h[i] = (_Float16)o1w[i];
  } else {
    int i = t - 65536;
    o2h[i] = (_Float16)o2w[i];
  }
}

// ---------------- kernel A: k,v GEMM + LayerNorm + kv outer-product partials --
// Grid 2048 = 8 b * 256 cb; each block: 4 chunks of 64 px. Wave w owns heads 2w,2w+1.
// LN: mean pre-folded into kvw; only s2 butterfly + v_sqrt + v_rcp remain.
// launch_bounds(256,5): 20 waves/CU (was 12).
__global__ __launch_bounds__(256, 5)
void k_qkv_kv(const float* __restrict__ x, const _Float16* __restrict__ kvw,
              const float* __restrict__ klw, const float* __restrict__ klb,
              const float* __restrict__ vlw, const float* __restrict__ vlb,
              float* __restrict__ partial) {
  __shared__ _Float16 xs[64][136];               // [pixel][channel], pad to 136
  const int t = threadIdx.x;
  const int lane = t & 63, w = t >> 6;
  const int quad = lane >> 4, l16 = lane & 15;
  const int b = blockIdx.x >> 8, cb = blockIdx.x & 255;
  const float* xb = x + (long)b * 8388608;       // b*128*65536

  float kw0[2], kb0[2], vw0[2], vb0[2];
#pragma unroll
  for (int hh = 0; hh < 2; hh++) {
    int h = 2 * w + hh;
    kw0[hh] = klw[h * 16 + l16]; kb0[hh] = klb[h * 16 + l16];
    vw0[hh] = vlw[h * 16 + l16]; vb0[hh] = vlb[h * 16 + l16];
  }

  float4_t kvacc[2] = {};                        // kv accumulator, C-layout

  for (int ch = 0; ch < 4; ch++) {
    const int n0 = cb * 256 + ch * 64;
    // stage x tile -> LDS fp16, [p][c]
#pragma unroll
    for (int i = 0; i < 8; i++) {
      int f = i * 256 + t;
      int c = f >> 4, pg = f & 15;
      float4 v = *(const float4*)(xb + ((long)c << 16) + n0 + 4 * pg);
      xs[4 * pg + 0][c] = (_Float16)v.x;
      xs[4 * pg + 1][c] = (_Float16)v.y;
      xs[4 * pg + 2][c] = (_Float16)v.z;
      xs[4 * pg + 3][c] = (_Float16)v.w;
    }
    __syncthreads();

    // C[p][och] = X[p][c] * Wkv[och][c]; wave och slice = [64w, 64w+64)
    float4_t acc[4][4] = {};                     // [m-tile][o-tile]
#pragma unroll
    for (int k = 0; k < 4; k++) {
      half8_t A[4];
#pragma unroll
      for (int mt = 0; mt < 4; mt++)
        A[mt] = *(const half8_t*)&xs[mt * 16 + l16][k * 32 + quad * 8];
#pragma unroll
      for (int ot = 0; ot < 4; ot++) {
        half8_t Bf = *(const half8_t*)(kvw + (w * 64 + ot * 16 + l16) * 128 + k * 32 + quad * 8);
#pragma unroll
        for (int mt = 0; mt < 4; mt++)
          acc[mt][ot] = __builtin_amdgcn_mfma_f32_16x16x32_f16(A[mt], Bf, acc[mt][ot], 0, 0, 0);
      }
    }

    // LN(k), LN(v) with pre-centered k',v': std = sqrt(sum(k'^2)/15) (unbiased),
    // inv = rcp(std + EPS).  Then kv += K^T V via 16x16x16 MFMA.
#pragma unroll
    for (int hh = 0; hh < 2; hh++) {
#pragma unroll
      for (int mt = 0; mt < 4; mt++) {
        half4_t kf, vf;
#pragma unroll
        for (int rr = 0; rr < 4; rr++) {
          float kx = acc[mt][2 * hh + 0][rr];
          float vx = acc[mt][2 * hh + 1][rr];
          float s2k = rsum16(kx * kx);
          float s2v = rsum16(vx * vx);
          // sqrt(s2/15) = sqrt(s2) * (1/sqrt(15));  rcp/sqrt are ~1ulp HW approx
          float rk = __builtin_amdgcn_rcpf(
              __builtin_fmaf(__builtin_amdgcn_sqrtf(s2k), 0.25819889f, EPS));
          float rv = __builtin_amdgcn_rcpf(
              __builtin_fmaf(__builtin_amdgcn_sqrtf(s2v), 0.25819889f, EPS));
          kf[rr] = (_Float16)((kw0[hh] * rk) * kx + kb0[hh]);
          vf[rr] = (_Float16)((vw0[hh] * rv) * vx + vb0[hh]);
        }
        kvacc[hh] = __builtin_amdgcn_mfma_f32_16x16x16f16(kf, vf, kvacc[hh], 0, 0, 0);
      }
    }
    __syncthreads();
  }

  // write per-block partial kv: [block][h][d][e]
#pragma unroll
  for (int hh = 0; hh < 2; hh++) {
    int h = 2 * w + hh;
#pragma unroll
    for (int rr = 0; rr < 4; rr++) {
      int d = quad * 4 + rr;
      partial[((long)blockIdx.x * 8 + h) * 256 + d * 16 + l16] = kvacc[hh][rr];
    }
  }
}

// ---------------- reducer: sum partials, /N, store transposed kvT[b][h][e][d] --
__global__ __launch_bounds__(256)
void k_reduce(const float* __restrict__ partial, float* __restrict__ kvT) {
  const int bh = blockIdx.x;                     // b*8+h
  const int t = threadIdx.x;                     // d*16+e
  const int b = bh >> 3, h = bh & 7;
  float s = 0.0f;
#pragma unroll 8
  for (int cb = 0; cb < 256; cb++)
    s += partial[((long)(b * 256 + cb) * 8 + h) * 256 + t];
  kvT[(bh << 8) + (t & 15) * 16 + (t >> 4)] = s * (1.0f / 65536.0f);
}

// ---------------- shared GEMM helper: C[p][och], och slice [32w,32w+32) -------
__device__ __forceinline__ void gemm_128(const _Float16* src, const _Float16* wgt,
                                         int w, int l16, int quad, float4_t (&acc)[4][2]) {
#pragma unroll
  for (int k = 0; k < 4; k++) {
    half8_t A[4];
#pragma unroll
    for (int mt = 0; mt < 4; mt++)
      A[mt] = *(const half8_t*)(src + (mt * 16 + l16) * 136 + k * 32 + quad * 8);
#pragma unroll
    for (int ot = 0; ot < 2; ot++) {
      half8_t Bf = *(const half8_t*)(wgt + (w * 32 + ot * 16 + l16) * 128 + k * 32 + quad * 8);
#pragma unroll
      for (int mt = 0; mt < 4; mt++)
        acc[mt][ot] = __builtin_amdgcn_mfma_f32_16x16x32_f16(A[mt], Bf, acc[mt][ot], 0, 0, 0);
    }
  }
}

// ---------------- kernel C: q GEMM + q@kv + residual + o1/gelu + o2/gelu ------
// Two LDS buffers (34.8 KB) instead of three: q->ret written in place (wave-
// exclusive columns), y-residual x snapshotted to 32 half regs before u
// overwrites bufA.  4 blocks/CU (was 3).
__global__ __launch_bounds__(256, 4)
void k_attn_out(const float* __restrict__ x, const _Float16* __restrict__ qw,
                const _Float16* __restrict__ o1h, const _Float16* __restrict__ o2h,
                const float* __restrict__ kvT, float* __restrict__ out) {
  __shared__ _Float16 bufA[64][136];             // x, later u
  __shared__ _Float16 bufB[64][136];             // q -> ret (in place), later y
  const int t = threadIdx.x;
  const int lane = t & 63, w = t >> 6;
  const int quad = lane >> 4, l16 = lane & 15;
  const int b = blockIdx.x >> 10;
  const int n0 = (blockIdx.x & 1023) << 6;
  const float* xb = x + (long)b * 8388608;

#pragma unroll
  for (int i = 0; i < 8; i++) {
    int f = i * 256 + t, c = f >> 4, pg = f & 15;
    float4 v = *(const float4*)(xb + ((long)c << 16) + n0 + 4 * pg);
    bufA[4 * pg + 0][c] = (_Float16)v.x;
    bufA[4 * pg + 1][c] = (_Float16)v.y;
    bufA[4 * pg + 2][c] = (_Float16)v.z;
    bufA[4 * pg + 3][c] = (_Float16)v.w;
  }

  // preload kv B-fragments for this wave's 2 heads: B[k=d][n=e] from kvT[b][h][e][d]
  half4_t kvf[2];
#pragma unroll
  for (int hh = 0; hh < 2; hh++) {
    int h = 2 * w + hh;
    float4 kq = *(const float4*)(kvT + ((b * 8 + h) << 8) + l16 * 16 + quad * 4);
    kvf[hh][0] = (_Float16)kq.x; kvf[hh][1] = (_Float16)kq.y;
    kvf[hh][2] = (_Float16)kq.z; kvf[hh][3] = (_Float16)kq.w;
  }
  __syncthreads();

  // q = x @ qw^T  (och slice [32w,32w+32)) -> bufB
  float4_t qa[4][2] = {};
  gemm_128(&bufA[0][0], qw, w, l16, quad, qa);
#pragma unroll
  for (int mt = 0; mt < 4; mt++)
#pragma unroll
    for (int ot = 0; ot < 2; ot++)
#pragma unroll
      for (int rr = 0; rr < 4; rr++)
        bufB[mt * 16 + quad * 4 + rr][w * 32 + ot * 16 + l16] = (_Float16)qa[mt][ot][rr];

  // o = q @ kv ; ret = o + x  (in place over q: wave-exclusive columns, in-wave
  // DS ordering guarantees the qf reads of iteration (hh,mt) complete before
  // the same wave's ret writes to the same 16-row block)
#pragma unroll
  for (int hh = 0; hh < 2; hh++) {
    int h = 2 * w + hh;
#pragma unroll
    for (int mt = 0; mt < 4; mt++) {
      half4_t qf = *(const half4_t*)&bufB[mt * 16 + l16][h * 16 + quad * 4];
      float4_t oacc = {};
      oacc = __builtin_amdgcn_mfma_f32_16x16x16f16(qf, kvf[hh], oacc, 0, 0, 0);
#pragma unroll
      for (int rr = 0; rr < 4; rr++) {
        int p = mt * 16 + quad * 4 + rr, c = h * 16 + l16;
        bufB[p][c] = (_Float16)(oacc[rr] + (float)bufA[p][c]);
      }
    }
  }

  // snapshot the y-stage residual x values before bufA is overwritten by u
  _Float16 xres[4][2][4];                        // static indexing -> registers
#pragma unroll
  for (int mt = 0; mt < 4; mt++)
#pragma unroll
    for (int ot = 0; ot < 2; ot++)
#pragma unroll
      for (int rr = 0; rr < 4; rr++)
        xres[mt][ot][rr] = bufA[mt * 16 + quad * 4 + rr][w * 32 + ot * 16 + l16];
  __syncthreads();                               // ret complete + bufA reads done

  // u = gelu(ret @ o1^T) -> bufA
  float4_t ua[4][2] = {};
  gemm_128(&bufB[0][0], o1h, w, l16, quad, ua);
#pragma unroll
  for (int mt = 0; mt < 4; mt++)
#pragma unroll
    for (int ot = 0; ot < 2; ot++)
#pragma unroll
      for (int rr = 0; rr < 4; rr++)
        bufA[mt * 16 + quad * 4 + rr][w * 32 + ot * 16 + l16] = (_Float16)gelu_f(ua[mt][ot][rr]);
  __syncthreads();

  // y = gelu(u @ o2^T + x) -> bufB (ret dead: all bufB reads done at barrier)
  float4_t ya[4][2] = {};
  gemm_128(&bufA[0][0], o2h, w, l16, quad, ya);
#pragma unroll
  for (int mt = 0; mt < 4; mt++)
#pragma unroll
    for (int ot = 0; ot < 2; ot++)
#pragma unroll
      for (int rr = 0; rr < 4; rr++) {
        int p = mt * 16 + quad * 4 + rr, c = w * 32 + ot * 16 + l16;
        bufB[p][c] = (_Float16)gelu_f(ya[mt][ot][rr] + (float)xres[mt][ot][rr]);
      }
  __syncthreads();

  // coalesced fp32 store via LDS transpose
#pragma unroll
  for (int i = 0; i < 8; i++) {
    int f = i * 256 + t, c = f >> 4, pg = f & 15;
    float4 o4;
    o4.x = (float)bufB[4 * pg + 0][c];
    o4.y = (float)bufB[4 * pg + 1][c];
    o4.z = (float)bufB[4 * pg + 2][c];
    o4.w = (float)bufB[4 * pg + 3][c];
    *(float4*)(out + ((long)b * 128 + c) * 65536 + n0 + 4 * pg) = o4;
  }
}

extern "C" void kernel_launch(void* const* d_in, const int* in_sizes, int n_in,
                              void* d_out, int out_size, void* d_ws, size_t ws_size,
                              hipStream_t stream) {
  const float* x    = (const float*)d_in[0];
  const float* qkvw = (const float*)d_in[1];
  const float* o1w  = (const float*)d_in[2];
  const float* o2w  = (const float*)d_in[3];
  const float* klw  = (const float*)d_in[4];
  const float* klb  = (const float*)d_in[5];
  const float* vlw  = (const float*)d_in[6];
  const float* vlb  = (const float*)d_in[7];
  float* out = (float*)d_out;
  char* ws = (char*)d_ws;
  _Float16* kvw  = (_Float16*)(ws + 0);        // 256x128 fp16   (64 KB)
  _Float16* qw   = (_Float16*)(ws + 65536);    // 128x128 fp16   (32 KB)
  _Float16* o1h  = (_Float16*)(ws + 98304);    // 128x128 fp16   (32 KB)
  _Float16* o2h  = (_Float16*)(ws + 131072);   // 128x128 fp16   (32 KB)
  float* kvT     = (float*)(ws + 163840);      // 8x8x16x16 fp32 (64 KB)
  float* partial = (float*)(ws + 229376);      // 2048x8x256 fp32 (16 MB)

  k_wconv<<<320, 256, 0, stream>>>(qkvw, o1w, o2w, kvw, qw, o1h, o2h);
  k_qkv_kv<<<2048, 256, 0, stream>>>(x, kvw, klw, klb, vlw, vlb, partial);
  k_reduce<<<64, 256, 0, stream>>>(partial, kvT);
  k_attn_out<<<8192, 256, 0, stream>>>(x, qw, o1h, o2h, kvT, out);
}